// Round 5
// baseline (139.804 us; speedup 1.0000x reference)
//
#include <hip/hip_runtime.h>
#include <math.h>

#define NB 4096
#define NF 2048
#define NM 14
#define NC 100
#define NK 16384

__device__ __forceinline__ float softplus_f(float v) {
    return fmaxf(v, 0.f) + log1pf(__expf(-fabsf(v)));
}

// kA: fused producer.
//  blocks [0,1024):    k1 — le_part[quarter][row][j] = x[row, quarter-of-F]·alpha[j, quarter]
//      grid = 256 rowgroups x 4 quarters; 16 rows/block, 4 rows/wave, 2 cc-chunks.
//      av[14] loaded once per chunk, amortized over 4 rows (proven k1 shape),
//      4 blocks/CU target for latency hiding.
//  blocks [1024,1280): k2 — SL[k] = (1/S_k, logS_k/S_k). Block 1024 zeroes cnt.
extern "C" __global__ void __launch_bounds__(256, 3) kA(
        const float* __restrict__ x, const float* __restrict__ alpha,
        float* __restrict__ le_part,
        const float* __restrict__ beta, const float* __restrict__ beta0,
        float2* __restrict__ SL, unsigned int* __restrict__ cnt) {
    const int tid = threadIdx.x;
    if (blockIdx.x < 1024) {
        // ---------------- k1: quarter-F GEMV ----------------
        const int wave = tid >> 6, lane = tid & 63;
        const int grp = (int)blockIdx.x >> 2;
        const int quarter = blockIdx.x & 3;
        const int row0 = grp * 16 + wave * 4;
        const float4* __restrict__ x4 = (const float4*)x;
        const float4* __restrict__ a4 = (const float4*)alpha;
        float acc[4][NM];
#pragma unroll
        for (int r = 0; r < 4; ++r)
#pragma unroll
            for (int j = 0; j < NM; ++j) acc[r][j] = 0.f;
#pragma unroll 1
        for (int cc = 0; cc < 2; ++cc) {
            const int f4i = quarter * 128 + cc * 64 + lane;
            float4 av[NM];
#pragma unroll
            for (int j = 0; j < NM; ++j) av[j] = a4[j * 512 + f4i];
#pragma unroll
            for (int r = 0; r < 4; ++r) {
                const float4 xv = x4[(row0 + r) * 512 + f4i];
#pragma unroll
                for (int j = 0; j < NM; ++j) {
                    acc[r][j] = fmaf(xv.x, av[j].x, acc[r][j]);
                    acc[r][j] = fmaf(xv.y, av[j].y, acc[r][j]);
                    acc[r][j] = fmaf(xv.z, av[j].z, acc[r][j]);
                    acc[r][j] = fmaf(xv.w, av[j].w, acc[r][j]);
                }
            }
        }
#pragma unroll
        for (int m = 1; m < 64; m <<= 1) {
#pragma unroll
            for (int r = 0; r < 4; ++r)
#pragma unroll
                for (int j = 0; j < NM; ++j)
                    acc[r][j] += __shfl_xor(acc[r][j], m, 64);
        }
        if (lane == 0) {
            float* dst = le_part + quarter * (NB * NM) + row0 * NM;
#pragma unroll
            for (int r = 0; r < 4; ++r)
#pragma unroll
                for (int j = 0; j < NM; ++j)
                    dst[r * NM + j] = acc[r][j];
        }
    } else {
        // ---------------- k2 ----------------
        __shared__ float b2[NC * NM];
        __shared__ float base_s[NC];
        __shared__ float Sp[4][64];
        const int kb = (int)blockIdx.x - 1024;
        if (kb == 0 && tid == 0) *cnt = 0u;
        for (int i = tid; i < NC * NM; i += 256) b2[i] = 2.f * beta[i];
        if (tid < NC) {
            float s = beta0[tid];
            for (int j = 0; j < NM; ++j) s -= beta[tid * NM + j];
            base_s[tid] = s;
        }
        __syncthreads();
        const int kl = tid & 63, q = tid >> 6;
        const int k = kb * 64 + kl;
        float bits[NM];
#pragma unroll
        for (int j = 0; j < NM; ++j) bits[j] = (float)((k >> (13 - j)) & 1);
        float S = 0.f;
        for (int c = q * 25; c < q * 25 + 25; ++c) {
            float d = base_s[c];
#pragma unroll
            for (int j = 0; j < NM; ++j) d = fmaf(bits[j], b2[c * NM + j], d);
            S += __expf(d);
        }
        Sp[q][kl] = S;
        __syncthreads();
        if (tid < 64) {
            const float Sf = Sp[0][tid] + Sp[1][tid] + Sp[2][tid] + Sp[3][tid];
            const float inv = 1.f / Sf;
            SL[kb * 64 + tid] = make_float2(inv, __logf(Sf) * inv);
        }
    }
}

// k3: 1024 blocks x 4 rows (halved per-block Phase-B chain, 4 blocks/CU = 16
// waves for latency hiding). U = sum_k exp(g-stab)/S, V = sum_k (../S)*(g-stab-logS),
// f_b = cs_b + V/U. Last block (ticket) reduces the 1024 partials.
extern "C" __global__ void __launch_bounds__(256, 4) k3_main(
        const float* __restrict__ le_part, const float* __restrict__ alpha0,
        const int* __restrict__ y, const float* __restrict__ beta,
        const float* __restrict__ beta0, const float2* __restrict__ SL,
        float* __restrict__ partial, unsigned int* __restrict__ cnt,
        float* __restrict__ out) {
    __shared__ float t_s[4][16];
    __shared__ float sp_s[4][16];
    __shared__ float cs_s[4];
    __shared__ float f_s[4];
    __shared__ float EAlds[128][4];  // exp(Ahi') * Ahi'
    __shared__ float Elds[128][4];   // exp(Ahi')
    __shared__ float red[4][8];
    __shared__ unsigned last_s;
    const int tid = threadIdx.x;
    const int b0 = blockIdx.x * 4;

    if (tid < 64) {
        const int r = tid >> 4, j = tid & 15;
        if (j < NM) {
            const int row = b0 + r;
            const int yv = y[row];
            const float lv = ((le_part[row * NM + j]
                             + le_part[NB * NM + row * NM + j])
                             + le_part[2 * NB * NM + row * NM + j])
                             + le_part[3 * NB * NM + row * NM + j] + alpha0[j];
            t_s[r][j] = lv + 2.f * beta[yv * NM + j];
            sp_s[r][j] = softplus_f(lv);
        }
    }
    __syncthreads();
    if (tid < 4) {
        const int yv = y[b0 + tid];
        float cs = beta0[yv];
        for (int j = 0; j < NM; ++j) {
            cs -= beta[yv * NM + j];
            cs += fmaxf(t_s[tid][j], 0.f) - sp_s[tid][j];  // stab - spsum
        }
        cs_s[tid] = cs;
    }
    // fill Ahi tables: 512 entries = 128 h x 4 rows
#pragma unroll
    for (int e = 0; e < 2; ++e) {
        const int idx = tid + 256 * e;
        const int r = idx & 3, h = idx >> 2;
        float A = 0.f, ub = 0.f;
#pragma unroll
        for (int j = 0; j < 7; ++j) {
            const float tv = t_s[r][j];
            A += ((h >> (6 - j)) & 1) ? tv : 0.f;
            ub += fmaxf(tv, 0.f);
        }
        const float Ap = A - ub;
        const float E = __expf(Ap);
        Elds[h][r] = E;
        EAlds[h][r] = E * Ap;
    }
    // per-thread Alo' and exp(Alo') per row (l = k & 127 = tid & 127)
    const int l = tid & 127;
    float eb[4], aterm[4];
#pragma unroll
    for (int r = 0; r < 4; ++r) {
        float A = 0.f, ub = 0.f;
#pragma unroll
        for (int j = 7; j < NM; ++j) {
            const float tv = t_s[r][j];
            A += ((l >> (13 - j)) & 1) ? tv : 0.f;
            ub += fmaxf(tv, 0.f);
        }
        aterm[r] = A - ub;
        eb[r] = __expf(A - ub);
    }
    __syncthreads();

    // ---------------- Phase B: inner reduction over k ----------------
    float U[4], V[4];
#pragma unroll
    for (int r = 0; r < 4; ++r) { U[r] = 0.f; V[r] = 0.f; }
    const int c = tid >> 7;   // wave-uniform
#pragma unroll 4
    for (int i = 0; i < 64; ++i) {
        const float2 sl = SL[i * 256 + tid];          // (1/S, logS/S) coalesced
        const float xw = sl.x;
        const float zw = sl.y;
        const int h = 2 * i + c;
        const float4 Pa = *(const float4*)&EAlds[h][0];
        const float4 Ea = *(const float4*)&Elds[h][0];
        const float Pr[4] = {Pa.x, Pa.y, Pa.z, Pa.w};
        const float Er[4] = {Ea.x, Ea.y, Ea.z, Ea.w};
#pragma unroll
        for (int r = 0; r < 4; ++r) {
            U[r] = fmaf(Er[r], xw, U[r]);
            V[r] = fmaf(Pr[r], xw, V[r]);
            V[r] = fmaf(Er[r], -zw, V[r]);
        }
    }
    // fold per-thread Alo' factor: u = eb*U, v = eb*(V + aterm*U)
    float vals[8];
#pragma unroll
    for (int r = 0; r < 4; ++r) {
        vals[r] = eb[r] * U[r];
        vals[4 + r] = eb[r] * fmaf(aterm[r], U[r], V[r]);
    }
#pragma unroll
    for (int m = 1; m < 64; m <<= 1)
#pragma unroll
        for (int q2 = 0; q2 < 8; ++q2)
            vals[q2] += __shfl_xor(vals[q2], m, 64);
    const int wv = tid >> 6, lane = tid & 63;
    if (lane == 0) {
#pragma unroll
        for (int q2 = 0; q2 < 8; ++q2) red[wv][q2] = vals[q2];
    }
    __syncthreads();
    if (tid < 8)
        red[0][tid] = red[0][tid] + red[1][tid] + red[2][tid] + red[3][tid];
    __syncthreads();
    if (tid < 4)
        f_s[tid] = cs_s[tid] + red[0][4 + tid] / red[0][tid];
    __syncthreads();
    if (tid == 0) {
        float s = 0.f;
#pragma unroll
        for (int r = 0; r < 4; ++r) s += f_s[r];
        __hip_atomic_store(&partial[blockIdx.x], s, __ATOMIC_RELEASE,
                           __HIP_MEMORY_SCOPE_AGENT);
        const unsigned old = __hip_atomic_fetch_add(cnt, 1u, __ATOMIC_ACQ_REL,
                                                    __HIP_MEMORY_SCOPE_AGENT);
        last_s = (old == 1023u) ? 1u : 0u;
    }
    __syncthreads();
    if (last_s) {
        // deterministic final reduce over 1024 partials
        float s = (__hip_atomic_load(&partial[tid], __ATOMIC_RELAXED,
                                     __HIP_MEMORY_SCOPE_AGENT)
                 + __hip_atomic_load(&partial[tid + 256], __ATOMIC_RELAXED,
                                     __HIP_MEMORY_SCOPE_AGENT))
                + (__hip_atomic_load(&partial[tid + 512], __ATOMIC_RELAXED,
                                     __HIP_MEMORY_SCOPE_AGENT)
                 + __hip_atomic_load(&partial[tid + 768], __ATOMIC_RELAXED,
                                     __HIP_MEMORY_SCOPE_AGENT));
#pragma unroll
        for (int m = 1; m < 64; m <<= 1) s += __shfl_xor(s, m, 64);
        if (lane == 0) red[0][wv] = s;
        __syncthreads();
        if (tid == 0) out[0] = red[0][0] + red[0][1] + red[0][2] + red[0][3];
    }
}

extern "C" void kernel_launch(void* const* d_in, const int* in_sizes, int n_in,
                              void* d_out, int out_size, void* d_ws, size_t ws_size,
                              hipStream_t stream) {
    const float* x      = (const float*)d_in[0];
    const int*   y      = (const int*)d_in[1];
    const float* alpha0 = (const float*)d_in[2];
    const float* alpha  = (const float*)d_in[3];
    const float* beta0  = (const float*)d_in[4];
    const float* beta   = (const float*)d_in[5];

    char* ws = (char*)d_ws;
    float*        le_part = (float*)ws;                        // 4*NB*NM*4 = 3.67 MB
    float2*       SL      = (float2*)(ws + 4 * NB * NM * 4);   // NK*8 = 131072 B
    float*        partial = (float*)(ws + 4 * NB * NM * 4 + NK * 8);   // 1024*4 B
    unsigned int* cnt     = (unsigned int*)(ws + 4 * NB * NM * 4 + NK * 8 + 1024 * 4);
    float*        out     = (float*)d_out;

    kA<<<1280, 256, 0, stream>>>(x, alpha, le_part, beta, beta0, SL, cnt);
    k3_main<<<1024, 256, 0, stream>>>(le_part, alpha0, y, beta, beta0, SL,
                                      partial, cnt, out);
}

// Round 6
// 117.822 us; speedup vs baseline: 1.1866x; 1.1866x over previous
//
#include <hip/hip_runtime.h>
#include <math.h>

#define NB 4096
#define NF 2048
#define NM 14
#define NC 100
#define NK 16384

typedef float f2 __attribute__((ext_vector_type(2)));  // packed f32 pair -> v_pk_fma_f32

__device__ __forceinline__ float softplus_f(float v) {
    return fmaxf(v, 0.f) + log1pf(__expf(-fabsf(v)));
}

// kA: fused producer kernel (round-1 proven shape).
//  blocks [0,512):   k1 — le_part[half][b][j] = x[b, half-of-F] . alpha[j, half-of-F]
//                    16 rows/block, 4 rows/wave, av[14] reused across 4 rows.
//  blocks [512,768): k2 — SL[k] = (1/S_k, logS_k/S_k). Block 512 zeroes cnt.
extern "C" __global__ void __launch_bounds__(256) kA(
        const float* __restrict__ x, const float* __restrict__ alpha,
        float* __restrict__ le_part,
        const float* __restrict__ beta, const float* __restrict__ beta0,
        float2* __restrict__ SL, unsigned int* __restrict__ cnt) {
    const int tid = threadIdx.x;
    if (blockIdx.x < 512) {
        // ---------------- k1 ----------------
        const int wave = tid >> 6, lane = tid & 63;
        const int grp = (int)blockIdx.x >> 1;
        const int half = blockIdx.x & 1;
        const int row0 = grp * 16 + wave * 4;
        const float4* __restrict__ x4 = (const float4*)x;
        const float4* __restrict__ a4 = (const float4*)alpha;
        float acc[4][NM];
#pragma unroll
        for (int r = 0; r < 4; ++r)
#pragma unroll
            for (int j = 0; j < NM; ++j) acc[r][j] = 0.f;
#pragma unroll 1
        for (int cc = 0; cc < 4; ++cc) {
            const int f4i = half * 256 + cc * 64 + lane;
            float4 av[NM];
#pragma unroll
            for (int j = 0; j < NM; ++j) av[j] = a4[j * 512 + f4i];
#pragma unroll
            for (int r = 0; r < 4; ++r) {
                const float4 xv = x4[(row0 + r) * 512 + f4i];
#pragma unroll
                for (int j = 0; j < NM; ++j) {
                    acc[r][j] = fmaf(xv.x, av[j].x, acc[r][j]);
                    acc[r][j] = fmaf(xv.y, av[j].y, acc[r][j]);
                    acc[r][j] = fmaf(xv.z, av[j].z, acc[r][j]);
                    acc[r][j] = fmaf(xv.w, av[j].w, acc[r][j]);
                }
            }
        }
#pragma unroll
        for (int m = 1; m < 64; m <<= 1) {
#pragma unroll
            for (int r = 0; r < 4; ++r)
#pragma unroll
                for (int j = 0; j < NM; ++j)
                    acc[r][j] += __shfl_xor(acc[r][j], m, 64);
        }
        if (lane == 0) {
            float* dst = le_part + half * (NB * NM) + row0 * NM;
#pragma unroll
            for (int r = 0; r < 4; ++r)
#pragma unroll
                for (int j = 0; j < NM; ++j)
                    dst[r * NM + j] = acc[r][j];
        }
    } else {
        // ---------------- k2 ----------------
        __shared__ float b2[NC * NM];
        __shared__ float base_s[NC];
        __shared__ float Sp[4][64];
        const int kb = (int)blockIdx.x - 512;
        if (kb == 0 && tid == 0) *cnt = 0u;
        for (int i = tid; i < NC * NM; i += 256) b2[i] = 2.f * beta[i];
        if (tid < NC) {
            float s = beta0[tid];
            for (int j = 0; j < NM; ++j) s -= beta[tid * NM + j];
            base_s[tid] = s;
        }
        __syncthreads();
        const int kl = tid & 63, q = tid >> 6;
        const int k = kb * 64 + kl;
        float bits[NM];
#pragma unroll
        for (int j = 0; j < NM; ++j) bits[j] = (float)((k >> (13 - j)) & 1);
        float S = 0.f;
        for (int c = q * 25; c < q * 25 + 25; ++c) {
            float d = base_s[c];
#pragma unroll
            for (int j = 0; j < NM; ++j) d = fmaf(bits[j], b2[c * NM + j], d);
            S += __expf(d);
        }
        Sp[q][kl] = S;
        __syncthreads();
        if (tid < 64) {
            const float Sf = Sp[0][tid] + Sp[1][tid] + Sp[2][tid] + Sp[3][tid];
            const float inv = 1.f / Sf;
            SL[kb * 64 + tid] = make_float2(inv, __logf(Sf) * inv);
        }
    }
}

// k3: round-1 proven structure (512 blocks x 8 rows), with Phase B recast as
// packed-f32 pairs: U2/V2 are float2 ext-vectors over row pairs so the inner
// 24 fma/iter become 12 v_pk_fma_f32. Last block (atomic ticket) does the
// deterministic 512-partial reduction.
extern "C" __global__ void __launch_bounds__(256, 2) k3_main(
        const float* __restrict__ le_part, const float* __restrict__ alpha0,
        const int* __restrict__ y, const float* __restrict__ beta,
        const float* __restrict__ beta0, const float2* __restrict__ SL,
        float* __restrict__ partial, unsigned int* __restrict__ cnt,
        float* __restrict__ out) {
    __shared__ float t_s[8][16];
    __shared__ float sp_s[8][16];
    __shared__ float cs_s[8];
    __shared__ float f_s[8];
    __shared__ float EAlds[128][8];  // exp(Ahi') * Ahi'
    __shared__ float Elds[128][8];   // exp(Ahi')
    __shared__ float red[4][16];
    __shared__ unsigned last_s;
    const int tid = threadIdx.x;
    const int b0 = blockIdx.x * 8;

    if (tid < 128) {
        const int r = tid >> 4, j = tid & 15;
        if (j < NM) {
            const int yv = y[b0 + r];
            const float lv = le_part[(b0 + r) * NM + j]
                           + le_part[NB * NM + (b0 + r) * NM + j] + alpha0[j];
            t_s[r][j] = lv + 2.f * beta[yv * NM + j];
            sp_s[r][j] = softplus_f(lv);
        }
    }
    __syncthreads();
    if (tid < 8) {
        const int yv = y[b0 + tid];
        float cs = beta0[yv];
        for (int j = 0; j < NM; ++j) {
            cs -= beta[yv * NM + j];
            cs += fmaxf(t_s[tid][j], 0.f) - sp_s[tid][j];  // stab - spsum
        }
        cs_s[tid] = cs;
    }
    // fill Ahi tables: 1024 entries = 128 h x 8 rows
#pragma unroll
    for (int e = 0; e < 4; ++e) {
        const int idx = tid + 256 * e;
        const int r = idx & 7, h = idx >> 3;
        float A = 0.f, ub = 0.f;
#pragma unroll
        for (int j = 0; j < 7; ++j) {
            const float tv = t_s[r][j];
            A += ((h >> (6 - j)) & 1) ? tv : 0.f;
            ub += fmaxf(tv, 0.f);
        }
        const float Ap = A - ub;
        const float E = __expf(Ap);
        Elds[h][r] = E;
        EAlds[h][r] = E * Ap;
    }
    // per-thread Alo' and exp(Alo') per row (l = k & 127 = tid & 127)
    const int l = tid & 127;
    float eb[8], aterm[8];
#pragma unroll
    for (int r = 0; r < 8; ++r) {
        float A = 0.f, ub = 0.f;
#pragma unroll
        for (int j = 7; j < NM; ++j) {
            const float tv = t_s[r][j];
            A += ((l >> (13 - j)) & 1) ? tv : 0.f;
            ub += fmaxf(tv, 0.f);
        }
        aterm[r] = A - ub;
        eb[r] = __expf(A - ub);
    }
    __syncthreads();

    // ---------------- Phase B: packed-f32 inner reduction over k ----------------
    f2 U2[4], V2[4];
#pragma unroll
    for (int p = 0; p < 4; ++p) { U2[p] = (f2)0.f; V2[p] = (f2)0.f; }
    const int c = tid >> 7;   // wave-uniform
#pragma unroll 4
    for (int i = 0; i < 64; ++i) {
        const float2 sl = SL[i * 256 + tid];          // (1/S, logS/S) coalesced
        f2 xw2; xw2.x = sl.x; xw2.y = sl.x;
        f2 zw2; zw2.x = sl.y; zw2.y = sl.y;
        const int h = 2 * i + c;
        const f2* __restrict__ Ep = (const f2*)&Elds[h][0];   // 4 pairs, bcast read
        const f2* __restrict__ Pp = (const f2*)&EAlds[h][0];
#pragma unroll
        for (int p = 0; p < 4; ++p) {
            const f2 E = Ep[p];
            const f2 P = Pp[p];
            U2[p] += E * xw2;        // contracts to v_pk_fma_f32
            V2[p] += P * xw2;
            V2[p] -= E * zw2;
        }
    }
    // fold per-thread Alo' factor: u = eb*U, v = eb*(V + aterm*U)
    float vals[16];
#pragma unroll
    for (int p = 0; p < 4; ++p) {
        vals[2 * p]     = eb[2 * p]     * U2[p].x;
        vals[2 * p + 1] = eb[2 * p + 1] * U2[p].y;
        vals[8 + 2 * p]     = eb[2 * p]     * fmaf(aterm[2 * p],     U2[p].x, V2[p].x);
        vals[8 + 2 * p + 1] = eb[2 * p + 1] * fmaf(aterm[2 * p + 1], U2[p].y, V2[p].y);
    }
#pragma unroll
    for (int m = 1; m < 64; m <<= 1)
#pragma unroll
        for (int q2 = 0; q2 < 16; ++q2)
            vals[q2] += __shfl_xor(vals[q2], m, 64);
    const int wv = tid >> 6, lane = tid & 63;
    if (lane == 0) {
#pragma unroll
        for (int q2 = 0; q2 < 16; ++q2) red[wv][q2] = vals[q2];
    }
    __syncthreads();
    if (tid < 16)
        red[0][tid] = red[0][tid] + red[1][tid] + red[2][tid] + red[3][tid];
    __syncthreads();
    if (tid < 8)
        f_s[tid] = cs_s[tid] + red[0][8 + tid] / red[0][tid];
    __syncthreads();
    if (tid == 0) {
        float s = 0.f;
#pragma unroll
        for (int r = 0; r < 8; ++r) s += f_s[r];
        __hip_atomic_store(&partial[blockIdx.x], s, __ATOMIC_RELEASE,
                           __HIP_MEMORY_SCOPE_AGENT);
        const unsigned old = __hip_atomic_fetch_add(cnt, 1u, __ATOMIC_ACQ_REL,
                                                    __HIP_MEMORY_SCOPE_AGENT);
        last_s = (old == 511u) ? 1u : 0u;
    }
    __syncthreads();
    if (last_s) {
        // deterministic final reduce — same order as the former k4
        float s = __hip_atomic_load(&partial[tid], __ATOMIC_RELAXED,
                                    __HIP_MEMORY_SCOPE_AGENT)
                + __hip_atomic_load(&partial[tid + 256], __ATOMIC_RELAXED,
                                    __HIP_MEMORY_SCOPE_AGENT);
#pragma unroll
        for (int m = 1; m < 64; m <<= 1) s += __shfl_xor(s, m, 64);
        if (lane == 0) red[0][wv] = s;
        __syncthreads();
        if (tid == 0) out[0] = red[0][0] + red[0][1] + red[0][2] + red[0][3];
    }
}

extern "C" void kernel_launch(void* const* d_in, const int* in_sizes, int n_in,
                              void* d_out, int out_size, void* d_ws, size_t ws_size,
                              hipStream_t stream) {
    const float* x      = (const float*)d_in[0];
    const int*   y      = (const int*)d_in[1];
    const float* alpha0 = (const float*)d_in[2];
    const float* alpha  = (const float*)d_in[3];
    const float* beta0  = (const float*)d_in[4];
    const float* beta   = (const float*)d_in[5];

    char* ws = (char*)d_ws;
    float*        le_part = (float*)ws;                          // 2*NB*NM*4 = 458752 B
    float2*       SL      = (float2*)(ws + 2 * NB * NM * 4);     // NK*8 = 131072 B
    float*        partial = (float*)(ws + 2 * NB * NM * 4 + NK * 8);     // 512*4 B
    unsigned int* cnt     = (unsigned int*)(ws + 2 * NB * NM * 4 + NK * 8 + 512 * 4);
    float*        out     = (float*)d_out;

    kA<<<768, 256, 0, stream>>>(x, alpha, le_part, beta, beta0, SL, cnt);
    k3_main<<<512, 256, 0, stream>>>(le_part, alpha0, y, beta, beta0, SL,
                                     partial, cnt, out);
}

// Round 7
// 117.677 us; speedup vs baseline: 1.1880x; 1.0012x over previous
//
#include <hip/hip_runtime.h>
#include <math.h>

#define NB 4096
#define NF 2048
#define NM 14
#define NC 100
#define NK 16384

typedef float f2 __attribute__((ext_vector_type(2)));  // packed f32 pair -> v_pk_fma_f32

__device__ __forceinline__ float softplus_f(float v) {
    return fmaxf(v, 0.f) + log1pf(__expf(-fabsf(v)));
}

// kA: fused producer kernel (round-1 proven shape).
//  blocks [0,512):   k1 — le_part[half][b][j] = x[b, half-of-F] . alpha[j, half-of-F]
//                    16 rows/block, 4 rows/wave, av[14] reused across 4 rows.
//  blocks [512,768): k2 — SL[k] = (1/S_k, logS_k/S_k). Block 512 zeroes cnt.
extern "C" __global__ void __launch_bounds__(256) kA(
        const float* __restrict__ x, const float* __restrict__ alpha,
        float* __restrict__ le_part,
        const float* __restrict__ beta, const float* __restrict__ beta0,
        float2* __restrict__ SL, unsigned int* __restrict__ cnt) {
    const int tid = threadIdx.x;
    if (blockIdx.x < 512) {
        // ---------------- k1 ----------------
        const int wave = tid >> 6, lane = tid & 63;
        const int grp = (int)blockIdx.x >> 1;
        const int half = blockIdx.x & 1;
        const int row0 = grp * 16 + wave * 4;
        const float4* __restrict__ x4 = (const float4*)x;
        const float4* __restrict__ a4 = (const float4*)alpha;
        float acc[4][NM];
#pragma unroll
        for (int r = 0; r < 4; ++r)
#pragma unroll
            for (int j = 0; j < NM; ++j) acc[r][j] = 0.f;
#pragma unroll 1
        for (int cc = 0; cc < 4; ++cc) {
            const int f4i = half * 256 + cc * 64 + lane;
            float4 av[NM];
#pragma unroll
            for (int j = 0; j < NM; ++j) av[j] = a4[j * 512 + f4i];
#pragma unroll
            for (int r = 0; r < 4; ++r) {
                const float4 xv = x4[(row0 + r) * 512 + f4i];
#pragma unroll
                for (int j = 0; j < NM; ++j) {
                    acc[r][j] = fmaf(xv.x, av[j].x, acc[r][j]);
                    acc[r][j] = fmaf(xv.y, av[j].y, acc[r][j]);
                    acc[r][j] = fmaf(xv.z, av[j].z, acc[r][j]);
                    acc[r][j] = fmaf(xv.w, av[j].w, acc[r][j]);
                }
            }
        }
#pragma unroll
        for (int m = 1; m < 64; m <<= 1) {
#pragma unroll
            for (int r = 0; r < 4; ++r)
#pragma unroll
                for (int j = 0; j < NM; ++j)
                    acc[r][j] += __shfl_xor(acc[r][j], m, 64);
        }
        if (lane == 0) {
            float* dst = le_part + half * (NB * NM) + row0 * NM;
#pragma unroll
            for (int r = 0; r < 4; ++r)
#pragma unroll
                for (int j = 0; j < NM; ++j)
                    dst[r * NM + j] = acc[r][j];
        }
    } else {
        // ---------------- k2 ----------------
        __shared__ float b2[NC * NM];
        __shared__ float base_s[NC];
        __shared__ float Sp[4][64];
        const int kb = (int)blockIdx.x - 512;
        if (kb == 0 && tid == 0) *cnt = 0u;
        for (int i = tid; i < NC * NM; i += 256) b2[i] = 2.f * beta[i];
        if (tid < NC) {
            float s = beta0[tid];
            for (int j = 0; j < NM; ++j) s -= beta[tid * NM + j];
            base_s[tid] = s;
        }
        __syncthreads();
        const int kl = tid & 63, q = tid >> 6;
        const int k = kb * 64 + kl;
        float bits[NM];
#pragma unroll
        for (int j = 0; j < NM; ++j) bits[j] = (float)((k >> (13 - j)) & 1);
        float S = 0.f;
        for (int c = q * 25; c < q * 25 + 25; ++c) {
            float d = base_s[c];
#pragma unroll
            for (int j = 0; j < NM; ++j) d = fmaf(bits[j], b2[c * NM + j], d);
            S += __expf(d);
        }
        Sp[q][kl] = S;
        __syncthreads();
        if (tid < 64) {
            const float Sf = Sp[0][tid] + Sp[1][tid] + Sp[2][tid] + Sp[3][tid];
            const float inv = 1.f / Sf;
            SL[kb * 64 + tid] = make_float2(inv, __logf(Sf) * inv);
        }
    }
}

// k3: 512 blocks x 8 rows, now 512 THREADS/block (8 waves): k-range split
// within the block (tid<256 -> i=0..31, tid>=256 -> i=32..63; k=i*256+(tid&255)).
// Same total SL-load/LDS issue as round-1, but 4 waves/SIMD instead of 2 to
// hide the L2-resident SL latency (VALUBusy ~30% -> latency-bound diagnosis).
// U/V combined by the in-block 8-wave reduction (fixed order, deterministic).
extern "C" __global__ void __launch_bounds__(512, 4) k3_main(
        const float* __restrict__ le_part, const float* __restrict__ alpha0,
        const int* __restrict__ y, const float* __restrict__ beta,
        const float* __restrict__ beta0, const float2* __restrict__ SL,
        float* __restrict__ partial, unsigned int* __restrict__ cnt,
        float* __restrict__ out) {
    __shared__ float t_s[8][16];
    __shared__ float sp_s[8][16];
    __shared__ float cs_s[8];
    __shared__ float f_s[8];
    __shared__ float EAlds[128][8];  // exp(Ahi') * Ahi'
    __shared__ float Elds[128][8];   // exp(Ahi')
    __shared__ float red[8][16];
    __shared__ unsigned last_s;
    const int tid = threadIdx.x;
    const int b0 = blockIdx.x * 8;

    if (tid < 128) {
        const int r = tid >> 4, j = tid & 15;
        if (j < NM) {
            const int yv = y[b0 + r];
            const float lv = le_part[(b0 + r) * NM + j]
                           + le_part[NB * NM + (b0 + r) * NM + j] + alpha0[j];
            t_s[r][j] = lv + 2.f * beta[yv * NM + j];
            sp_s[r][j] = softplus_f(lv);
        }
    }
    __syncthreads();
    if (tid < 8) {
        const int yv = y[b0 + tid];
        float cs = beta0[yv];
        for (int j = 0; j < NM; ++j) {
            cs -= beta[yv * NM + j];
            cs += fmaxf(t_s[tid][j], 0.f) - sp_s[tid][j];  // stab - spsum
        }
        cs_s[tid] = cs;
    }
    // fill Ahi tables: 1024 entries = 128 h x 8 rows (512 threads, 2 each)
#pragma unroll
    for (int e = 0; e < 2; ++e) {
        const int idx = tid + 512 * e;
        const int r = idx & 7, h = idx >> 3;
        float A = 0.f, ub = 0.f;
#pragma unroll
        for (int j = 0; j < 7; ++j) {
            const float tv = t_s[r][j];
            A += ((h >> (6 - j)) & 1) ? tv : 0.f;
            ub += fmaxf(tv, 0.f);
        }
        const float Ap = A - ub;
        const float E = __expf(Ap);
        Elds[h][r] = E;
        EAlds[h][r] = E * Ap;
    }
    // per-thread Alo' and exp(Alo') per row (l = k & 127 = tid & 127)
    const int l = tid & 127;
    float eb[8], aterm[8];
#pragma unroll
    for (int r = 0; r < 8; ++r) {
        float A = 0.f, ub = 0.f;
#pragma unroll
        for (int j = 7; j < NM; ++j) {
            const float tv = t_s[r][j];
            A += ((l >> (13 - j)) & 1) ? tv : 0.f;
            ub += fmaxf(tv, 0.f);
        }
        aterm[r] = A - ub;
        eb[r] = __expf(A - ub);
    }
    __syncthreads();

    // ---------------- Phase B: packed-f32 inner reduction over half k-range ----
    f2 U2[4], V2[4];
#pragma unroll
    for (int p = 0; p < 4; ++p) { U2[p] = (f2)0.f; V2[p] = (f2)0.f; }
    const int t8 = tid & 255;
    const int c = t8 >> 7;            // wave-uniform
    const int i0 = (tid >> 8) * 32;   // 0 or 32
#pragma unroll 4
    for (int ii = 0; ii < 32; ++ii) {
        const int i = i0 + ii;
        const float2 sl = SL[i * 256 + t8];           // (1/S, logS/S) coalesced
        f2 xw2; xw2.x = sl.x; xw2.y = sl.x;
        f2 zw2; zw2.x = sl.y; zw2.y = sl.y;
        const int h = 2 * i + c;
        const f2* __restrict__ Ep = (const f2*)&Elds[h][0];   // 4 pairs, bcast read
        const f2* __restrict__ Pp = (const f2*)&EAlds[h][0];
#pragma unroll
        for (int p = 0; p < 4; ++p) {
            const f2 E = Ep[p];
            const f2 P = Pp[p];
            U2[p] += E * xw2;        // contracts to v_pk_fma_f32
            V2[p] += P * xw2;
            V2[p] -= E * zw2;
        }
    }
    // fold per-thread Alo' factor: u = eb*U, v = eb*(V + aterm*U)
    float vals[16];
#pragma unroll
    for (int p = 0; p < 4; ++p) {
        vals[2 * p]     = eb[2 * p]     * U2[p].x;
        vals[2 * p + 1] = eb[2 * p + 1] * U2[p].y;
        vals[8 + 2 * p]     = eb[2 * p]     * fmaf(aterm[2 * p],     U2[p].x, V2[p].x);
        vals[8 + 2 * p + 1] = eb[2 * p + 1] * fmaf(aterm[2 * p + 1], U2[p].y, V2[p].y);
    }
#pragma unroll
    for (int m = 1; m < 64; m <<= 1)
#pragma unroll
        for (int q2 = 0; q2 < 16; ++q2)
            vals[q2] += __shfl_xor(vals[q2], m, 64);
    const int wv = tid >> 6, lane = tid & 63;   // wv in 0..7
    if (lane == 0) {
#pragma unroll
        for (int q2 = 0; q2 < 16; ++q2) red[wv][q2] = vals[q2];
    }
    __syncthreads();
    if (tid < 16) {
        float s = red[0][tid];
#pragma unroll
        for (int w = 1; w < 8; ++w) s += red[w][tid];   // fixed order, deterministic
        red[0][tid] = s;
    }
    __syncthreads();
    if (tid < 8)
        f_s[tid] = cs_s[tid] + red[0][8 + tid] / red[0][tid];
    __syncthreads();
    if (tid == 0) {
        float s = 0.f;
#pragma unroll
        for (int r = 0; r < 8; ++r) s += f_s[r];
        __hip_atomic_store(&partial[blockIdx.x], s, __ATOMIC_RELEASE,
                           __HIP_MEMORY_SCOPE_AGENT);
        const unsigned old = __hip_atomic_fetch_add(cnt, 1u, __ATOMIC_ACQ_REL,
                                                    __HIP_MEMORY_SCOPE_AGENT);
        last_s = (old == 511u) ? 1u : 0u;
    }
    __syncthreads();
    if (last_s) {
        // deterministic final reduce: 512 threads cover 512 partials exactly
        float s = __hip_atomic_load(&partial[tid], __ATOMIC_RELAXED,
                                    __HIP_MEMORY_SCOPE_AGENT);
#pragma unroll
        for (int m = 1; m < 64; m <<= 1) s += __shfl_xor(s, m, 64);
        if (lane == 0) red[wv][0] = s;
        __syncthreads();
        if (tid == 0) {
            float t = red[0][0];
#pragma unroll
            for (int w = 1; w < 8; ++w) t += red[w][0];
            out[0] = t;
        }
    }
}

extern "C" void kernel_launch(void* const* d_in, const int* in_sizes, int n_in,
                              void* d_out, int out_size, void* d_ws, size_t ws_size,
                              hipStream_t stream) {
    const float* x      = (const float*)d_in[0];
    const int*   y      = (const int*)d_in[1];
    const float* alpha0 = (const float*)d_in[2];
    const float* alpha  = (const float*)d_in[3];
    const float* beta0  = (const float*)d_in[4];
    const float* beta   = (const float*)d_in[5];

    char* ws = (char*)d_ws;
    float*        le_part = (float*)ws;                          // 2*NB*NM*4 = 458752 B
    float2*       SL      = (float2*)(ws + 2 * NB * NM * 4);     // NK*8 = 131072 B
    float*        partial = (float*)(ws + 2 * NB * NM * 4 + NK * 8);     // 512*4 B
    unsigned int* cnt     = (unsigned int*)(ws + 2 * NB * NM * 4 + NK * 8 + 512 * 4);
    float*        out     = (float*)d_out;

    kA<<<768, 256, 0, stream>>>(x, alpha, le_part, beta, beta0, SL, cnt);
    k3_main<<<512, 512, 0, stream>>>(le_part, alpha0, y, beta, beta0, SL,
                                     partial, cnt, out);
}